// Round 5
// baseline (141.728 us; speedup 1.0000x reference)
//
#include <hip/hip_runtime.h>
#include <hip/hip_bf16.h>
#include <cstdint>
#include <cstddef>

#define BATCH   8192
#define NSAMP   8192
#define DIM     512
#define NCLASS  50000

typedef __attribute__((ext_vector_type(8))) short bf16x8;
typedef __attribute__((ext_vector_type(4))) float f32x4;

// -log(expected_count(c)) for the log-uniform sampler, in double to match the
// numpy reference (f32 log(c+2)-log(c+1) catastrophically cancels at large c).
__device__ __forceinline__ float neg_log_expected(int c) {
    double p = log1p(1.0 / (double)(c + 1)) / log((double)(NCLASS + 1));
    double e = -expm1((double)NSAMP * log1p(-p));
    return (float)(-log(e));
}

__device__ __forceinline__ unsigned short f2bf(float f) {
    __hip_bfloat16 h = __float2bfloat16(f);
    return *reinterpret_cast<unsigned short*>(&h);
}

__device__ __forceinline__ void gload_lds16(const void* g, void* l) {
    __builtin_amdgcn_global_load_lds(
        (const __attribute__((address_space(1))) void*)g,
        (__attribute__((address_space(3))) void*)l, 16, 0, 0);
}

// ---- kernel 1: fused inputs f32->bf16 + true-logit + row_sum seed ----------
__global__ void k_fused(const float* __restrict__ inputs, const int* __restrict__ labels,
                        const float* __restrict__ W, const float* __restrict__ bias,
                        __hip_bfloat16* __restrict__ Abf,
                        float* __restrict__ true_logit, float* __restrict__ row_sum) {
    int row = blockIdx.x;
    int t   = threadIdx.x;                       // 0..127
    float4 v = reinterpret_cast<const float4*>(inputs + (size_t)row * DIM)[t];
    ushort4 u;
    u.x = f2bf(v.x); u.y = f2bf(v.y); u.z = f2bf(v.z); u.w = f2bf(v.w);
    reinterpret_cast<ushort4*>(Abf + (size_t)row * DIM)[t] = u;

    int lbl = labels[row];
    float4 w = reinterpret_cast<const float4*>(W + (size_t)lbl * DIM)[t];
    float dot = v.x * w.x + v.y * w.y + v.z * w.z + v.w * w.w;
    #pragma unroll
    for (int off = 32; off; off >>= 1) dot += __shfl_down(dot, off, 64);
    __shared__ float red[2];
    if ((t & 63) == 0) red[t >> 6] = dot;
    __syncthreads();
    if (t == 0) {
        float tl = red[0] + red[1] + bias[lbl] + neg_log_expected(lbl);
        true_logit[row] = tl;
        row_sum[row]    = __expf(tl);
    }
}

// ---- kernel 2: gather kernel[sampled] -> bf16 B; adj[s] = bias - log(expected)
__global__ void k_gather(const float* __restrict__ W, const float* __restrict__ bias,
                         const int* __restrict__ sampled,
                         __hip_bfloat16* __restrict__ Bbf, float* __restrict__ adj) {
    int s   = blockIdx.x;
    int idx = sampled[s];
    float4 v = reinterpret_cast<const float4*>(W + (size_t)idx * DIM)[threadIdx.x];
    ushort4 u;
    u.x = f2bf(v.x); u.y = f2bf(v.y); u.z = f2bf(v.z); u.w = f2bf(v.w);
    reinterpret_cast<ushort4*>(Bbf + (size_t)s * DIM)[threadIdx.x] = u;
    if (threadIdx.x == 0) adj[s] = bias[idx] + neg_log_expected(idx);
}

// ---- kernel 3: 8192x8192x512 bf16 GEMM ------------------------------------
// Round-4: BM=BN=128, BK=64, 4 waves (2x2), 256 threads, LDS 65KB ->
// 2 RESIDENT BLOCKS/CU (the H2 fix: co-resident block overlaps the other's
// barriers/prologue/epilogue; grid 4096 = 16 blocks/CU amortizes fill/drain).
// Kept from round 3: quadrant phases with reg-held halves, involutive granule
// swizzle (0 conflicts), counted VMCNT(6) ledger (identical), setprio,
// XCD-local rasterization (redone for the 64x64 tile grid).

#define BARRIER() asm volatile("s_barrier" ::: "memory")
#define VMCNT(n)  asm volatile("s_waitcnt vmcnt(" #n ")" ::: "memory")

#define READ_A(BUF, MH)                                                        \
    _Pragma("unroll")                                                          \
    for (int mi = 0; mi < 2; ++mi)                                             \
      _Pragma("unroll")                                                        \
      for (int ks = 0; ks < 2; ++ks)                                           \
        af[mi][ks] = *reinterpret_cast<const bf16x8*>(                         \
          &Asm[BUF][abase + (MH)*4096 + mi*2048 + (((ks*4) + gg) ^ axg)*8]);

#define READ_B(BUF, NH, DST)                                                   \
    _Pragma("unroll")                                                          \
    for (int ni = 0; ni < 2; ++ni)                                             \
      _Pragma("unroll")                                                        \
      for (int ks = 0; ks < 2; ++ks)                                           \
        DST[ni][ks] = *reinterpret_cast<const bf16x8*>(                        \
          &Bsm[BUF][bbase + (NH)*4096 + ni*2048 + (((ks*4) + gg) ^ axg)*8]);

#define MFMA_Q(MH, NH, BSRC)                                                   \
    __builtin_amdgcn_s_setprio(1);                                             \
    _Pragma("unroll")                                                          \
    for (int mi = 0; mi < 2; ++mi)                                             \
      _Pragma("unroll")                                                        \
      for (int ni = 0; ni < 2; ++ni)                                           \
        _Pragma("unroll")                                                      \
        for (int ks = 0; ks < 2; ++ks)                                         \
          acc[(MH)*2+mi][(NH)*2+ni] = __builtin_amdgcn_mfma_f32_16x16x32_bf16( \
            af[mi][ks], BSRC[ni][ks], acc[(MH)*2+mi][(NH)*2+ni], 0, 0, 0);     \
    __builtin_amdgcn_s_setprio(0);

__global__ __launch_bounds__(256, 2) void k_gemm(
    const __hip_bfloat16* __restrict__ A, const __hip_bfloat16* __restrict__ B,
    const float* __restrict__ adj, const int* __restrict__ labels,
    const int* __restrict__ sampled, float* __restrict__ row_sum) {
    __shared__ alignas(16) __hip_bfloat16 Asm[2][128 * 64];   // 32 KiB
    __shared__ alignas(16) __hip_bfloat16 Bsm[2][128 * 64];   // 32 KiB
    __shared__ float tsum[2][128];                            // 1 KiB

    const int tid  = threadIdx.x;
    const int wave = tid >> 6;
    const int lane = tid & 63;
    const int wr   = wave >> 1;          // 0..1  (M)
    const int wc   = wave & 1;           // 0..1  (N)

    // XCD-local rasterization over the 64x64 tile grid (bijective):
    // xcd = bid&7 owns tile-row band [xcd*8, xcd*8+8); sweeps cols slowly.
    // Working set per XCD: 1MB A-band (L2-resident) + ~1MB active B panels.
    const int bid  = blockIdx.x;
    const int xcd  = bid & 7;
    const int j    = bid >> 3;           // 0..511
    const int brow = ((xcd << 3) | (j & 7)) * 128;
    const int bcol = (j >> 3) * 128;

    // staging: lane covers row (l>>3) of an 8-row chunk, phys granule l&7;
    // fetch logical granule (l&7)^row (involution, both-sides)
    const int sr8 = lane >> 3;
    const int sg8 = (lane & 7) ^ sr8;

    // fragment read: row = MH*64+mi*32+wr*16+rsel; phys granule = logical^(row&7)
    const int rsel  = lane & 15;
    const int gg    = lane >> 4;
    const int axg   = rsel & 7;
    const int abase = (wr * 16 + rsel) * 64;
    const int bbase = (wc * 16 + rsel) * 64;

    f32x4 acc[4][4];
    #pragma unroll
    for (int m = 0; m < 4; ++m)
        #pragma unroll
        for (int n = 0; n < 4; ++n)
            acc[m][n] = (f32x4){0.f, 0.f, 0.f, 0.f};

    auto stageA = [&](int buf, int kt, int half) {
        #pragma unroll
        for (int i = 0; i < 2; ++i) {
            const int lrow = half * 64 + i * 32 + wave * 8;    // wave-uniform
            const __hip_bfloat16* g =
                A + (size_t)(brow + lrow + sr8) * DIM + kt * 64 + sg8 * 8;
            gload_lds16(g, &Asm[buf][lrow * 64]);
        }
    };
    auto stageB = [&](int buf, int kt, int half) {
        #pragma unroll
        for (int i = 0; i < 2; ++i) {
            const int lrow = half * 64 + i * 32 + wave * 8;
            const __hip_bfloat16* g =
                B + (size_t)(bcol + lrow + sr8) * DIM + kt * 64 + sg8 * 8;
            gload_lds16(g, &Bsm[buf][lrow * 64]);
        }
    };

    // prologue: tile 0, issue order = consumption order (Ah0, Bh0, Bh1, Ah1)
    stageA(0, 0, 0); stageB(0, 0, 0); stageB(0, 0, 1); stageA(0, 0, 1);

    bf16x8 af[2][2], bf0[2][2], bf1[2][2];

    #pragma unroll 1
    for (int t = 0; t < 7; ++t) {
        const int buf = t & 1, nb = buf ^ 1, nt = t + 1;
        // phase 0: quadrant (0,0) — consumes Ah0+Bh0
        stageA(nb, nt, 0); VMCNT(6); BARRIER();
        READ_A(buf, 0); READ_B(buf, 0, bf0); MFMA_Q(0, 0, bf0);
        // phase 1: quadrant (0,1) — consumes Bh1 (A h0 held)
        stageB(nb, nt, 0); VMCNT(6); BARRIER();
        READ_B(buf, 1, bf1); MFMA_Q(0, 1, bf1);
        // phase 2: quadrant (1,1) — consumes Ah1 (B h1 held)
        stageB(nb, nt, 1); VMCNT(6); BARRIER();
        READ_A(buf, 1); MFMA_Q(1, 1, bf1);
        // phase 3: quadrant (1,0) — all operands held in regs
        stageA(nb, nt, 1);
        MFMA_Q(1, 0, bf0);
        BARRIER();   // closing: all reads of buf done before next tile stages it
    }
    // peeled last tile (t = 7, buf = 1): drain 4 -> 2 -> 0
    {
        VMCNT(4); BARRIER();
        READ_A(1, 0); READ_B(1, 0, bf0); MFMA_Q(0, 0, bf0);
        VMCNT(2); BARRIER();
        READ_B(1, 1, bf1); MFMA_Q(0, 1, bf1);
        VMCNT(0); BARRIER();
        READ_A(1, 1); MFMA_Q(1, 1, bf1);
        MFMA_Q(1, 0, bf0);
    }

    // ---- epilogue ----------------------------------------------------------
    int sv[4]; float aadj[4];
    #pragma unroll
    for (int n = 0; n < 4; ++n) {
        int col = bcol + (n >> 1) * 64 + (n & 1) * 32 + wc * 16 + rsel;
        aadj[n] = adj[col];
        sv[n]   = sampled[col];
    }
    #pragma unroll
    for (int m = 0; m < 4; ++m) {
        #pragma unroll
        for (int r = 0; r < 4; ++r) {
            int lrow = (m >> 1) * 64 + (m & 1) * 32 + wr * 16 + gg * 4 + r;
            int lbl  = labels[brow + lrow];
            float part = 0.f;
            #pragma unroll
            for (int n = 0; n < 4; ++n) {
                float logit = acc[m][n][r] + aadj[n];
                part += (sv[n] == lbl) ? 0.f : __expf(logit);
            }
            part += __shfl_xor(part, 1, 16);
            part += __shfl_xor(part, 2, 16);
            part += __shfl_xor(part, 4, 16);
            part += __shfl_xor(part, 8, 16);
            if (rsel == 0) tsum[wc][lrow] = part;
        }
    }
    __syncthreads();
    if (tid < 128)
        atomicAdd(&row_sum[brow + tid], tsum[0][tid] + tsum[1][tid]);
}

// ---- kernel 4: loss = log(row_sum) - true_logit -----------------------------
__global__ void k_final(const float* __restrict__ row_sum,
                        const float* __restrict__ true_logit,
                        float* __restrict__ loss) {
    int i = blockIdx.x * blockDim.x + threadIdx.x;
    loss[i] = logf(row_sum[i]) - true_logit[i];
}

extern "C" void kernel_launch(void* const* d_in, const int* in_sizes, int n_in,
                              void* d_out, int out_size, void* d_ws, size_t ws_size,
                              hipStream_t stream) {
    const float* inputs  = (const float*)d_in[0];
    const int*   labels  = (const int*)d_in[1];
    const float* W       = (const float*)d_in[2];
    const float* bias    = (const float*)d_in[3];
    const int*   sampled = (const int*)d_in[4];
    float*       loss    = (float*)d_out;

    char* ws = (char*)d_ws;
    __hip_bfloat16* Abf = (__hip_bfloat16*)ws;                                  // 8 MiB
    __hip_bfloat16* Bbf = (__hip_bfloat16*)(ws + (size_t)BATCH * DIM * 2);      // 8 MiB
    float* adj        = (float*)(ws + (size_t)(BATCH + NSAMP) * DIM * 2);       // 32 KiB
    float* true_logit = adj + NSAMP;                                            // 32 KiB
    float* row_sum    = true_logit + BATCH;                                     // 32 KiB

    hipLaunchKernelGGL(k_fused, dim3(BATCH), dim3(128), 0, stream,
                       inputs, labels, W, bias, Abf, true_logit, row_sum);
    hipLaunchKernelGGL(k_gather, dim3(NSAMP), dim3(128), 0, stream,
                       W, bias, sampled, Bbf, adj);
    hipLaunchKernelGGL(k_gemm, dim3((BATCH / 128) * (NSAMP / 128)), dim3(256), 0, stream,
                       Abf, Bbf, adj, labels, sampled, row_sum);
    hipLaunchKernelGGL(k_final, dim3(BATCH / 256), dim3(256), 0, stream,
                       row_sum, true_logit, loss);
}